// Round 22
// baseline (166.673 us; speedup 1.0000x reference)
//
#include <hip/hip_runtime.h>
#include <cstdint>

#define HSZ 32
#define TSTEPS 256
#define ISZ 6
#define NB 8

typedef _Float16 h8_t __attribute__((ext_vector_type(8)));
typedef float f4_t __attribute__((ext_vector_type(4)));

#if __has_builtin(__builtin_amdgcn_exp2f)
__device__ __forceinline__ float exp2_raw(float x) { return __builtin_amdgcn_exp2f(x); }
#else
__device__ __forceinline__ float exp2_raw(float x) { return __expf(0.69314718056f * x); }
#endif

// Round-22 = round-21 resubmitted verbatim (infra failure, never ran).
// NB=8: 1024 single-wave blocks -> every SIMD occupied. r20's bug (hlds
// zero-init overflow into w1s) fixed: loop writes exactly 320 uints.
// Rationale recap: r19 had 512 waves on 1024 SIMDs (half chip idle, occupied
// SIMDs ~61% issue / ~39% exposed latency). NB=8 doubles resident waves;
// activation work halves (only khi<2 lanes hold real batches, one
// exec-masked issue); MFMA M-half wasted (MfmaUtil 8% -> not binding).
// A-rows 8-15 carry duplicated x (harmless: D row m depends only on A row m);
// hlds rows 8-15 stay zero; out-write guarded n16<8.
// Activation (r19 common-denominator, 7 trans/pair):
//   c' = [c(1+ei)(1+eg) + (1-eg)(1+ef)] * rcp((1+ef)(1+ei)(1+eg))
//   h  = (1-ec) * rcp((1+eo)(1+ec)),  ec = exp2(-2*log2e*c')
// Weights pre-scaled by -log2e (g rows -2log2e); bias preset in C-operand.
__global__ __launch_bounds__(64, 2) void lstm_wave(
    const float* __restrict__ x,
    const float* __restrict__ W_ih,
    const float* __restrict__ W_hh,
    const float* __restrict__ b_ih,
    const float* __restrict__ b_hh,
    const float* __restrict__ W1,
    const float* __restrict__ b1,
    const float* __restrict__ W2,
    const float* __restrict__ b2,
    float* __restrict__ out)
{
    __shared__ __align__(16) _Float16 hlds[16][40];   // h state, 80B rows; rows 8-15 stay 0
    __shared__ float w1s[64 * 34];                    // stride 34: even + conflict-free
    __shared__ float b1s[64];
    __shared__ float w2s[64];

    const int lane = threadIdx.x;
    const int n16  = lane & 15;
    const int khi  = lane >> 4;
    const int b8   = n16 & 7;        // batch index within block (lanes 8-15 dup)

    // ---- one-time staging ----
    for (int i = lane; i < 64 * HSZ; i += 64) w1s[(i >> 5) * 34 + (i & 31)] = W1[i];
    b1s[lane] = b1[lane];
    w2s[lane] = W2[lane];
    #pragma unroll
    for (int i = 0; i < 5; ++i) ((unsigned int*)hlds)[lane + i * 64] = 0u;  // 320 uints = all of hlds

    // B-fragments + bias, pre-scaled. Tile q: q0,1=i q2,3=f q4,5=g q6,7=o.
    const float LOG2E = 1.44269504f;
    h8_t bhh[8], bih[8];
    f4_t bias4[8];
    #pragma unroll
    for (int q = 0; q < 8; ++q) {
        const int grow = q * 16 + n16;
        const float s = (q == 4 || q == 5) ? (-2.0f * LOG2E) : (-LOG2E);
        const float4* p = (const float4*)(W_hh + grow * HSZ + khi * 8);
        const float4 a = p[0], b = p[1];
        bhh[q][0] = (_Float16)(s * a.x); bhh[q][1] = (_Float16)(s * a.y);
        bhh[q][2] = (_Float16)(s * a.z); bhh[q][3] = (_Float16)(s * a.w);
        bhh[q][4] = (_Float16)(s * b.x); bhh[q][5] = (_Float16)(s * b.y);
        bhh[q][6] = (_Float16)(s * b.z); bhh[q][7] = (_Float16)(s * b.w);
        const float bb = s * (b_ih[grow] + b_hh[grow]);
        bias4[q][0] = bb; bias4[q][1] = bb; bias4[q][2] = bb; bias4[q][3] = bb;
        bih[q][0] = (_Float16)0; bih[q][1] = (_Float16)0;
        bih[q][2] = (_Float16)0; bih[q][3] = (_Float16)0;
        bih[q][4] = (_Float16)0; bih[q][5] = (_Float16)0;
        bih[q][6] = (_Float16)0; bih[q][7] = (_Float16)0;
        if (khi == 0) {
            const float2* pi = (const float2*)(W_ih + grow * ISZ);
            const float2 i0 = pi[0], i1 = pi[1], i2 = pi[2];
            bih[q][0] = (_Float16)(s * i0.x); bih[q][1] = (_Float16)(s * i0.y);
            bih[q][2] = (_Float16)(s * i1.x); bih[q][3] = (_Float16)(s * i1.y);
            bih[q][4] = (_Float16)(s * i2.x); bih[q][5] = (_Float16)(s * i2.y);
        }
    }

    // x stream for batch b8 (lanes with same b8 share the addr -> broadcast).
    const float* xb = x + (size_t)(blockIdx.x * NB + b8) * (TSTEPS * ISZ);
    float2 xa0 = ((const float2*)xb)[0], xa1 = ((const float2*)xb)[1], xa2 = ((const float2*)xb)[2];
    const float2* pn1 = (const float2*)(xb + ISZ);
    float2 xn0 = pn1[0], xn1 = pn1[1], xn2 = pn1[2];

    float c[2][4] = {{0.f, 0.f, 0.f, 0.f}, {0.f, 0.f, 0.f, 0.f}};

    __builtin_amdgcn_wave_barrier();

    for (int t = 0; t < TSTEPS; ++t) {
        // A-fragments (hlds rows 0-7 = batches, 8-15 = zeros)
        const h8_t ah = *(const h8_t*)&hlds[n16][khi * 8];
        h8_t ax;
        ax[0] = (_Float16)xa0.x; ax[1] = (_Float16)xa0.y;
        ax[2] = (_Float16)xa1.x; ax[3] = (_Float16)xa1.y;
        ax[4] = (_Float16)xa2.x; ax[5] = (_Float16)xa2.y;
        ax[6] = (_Float16)0;     ax[7] = (_Float16)0;
        xa0 = xn0; xa1 = xn1; xa2 = xn2;
        const int tn = (t + 2 < TSTEPS) ? (t + 2) : (TSTEPS - 1);
        const float2* pn = (const float2*)(xb + tn * ISZ);
        xn0 = pn[0]; xn1 = pn[1]; xn2 = pn[2];

        // 16 MFMAs: x-part (K-padded, bias preset) then h-part chained.
        f4_t d[8];
        #pragma unroll
        for (int q = 0; q < 8; ++q)
            d[q] = __builtin_amdgcn_mfma_f32_16x16x32_f16(ax, bih[q], bias4[q], 0, 0, 0);
        #pragma unroll
        for (int q = 0; q < 8; ++q)
            d[q] = __builtin_amdgcn_mfma_f32_16x16x32_f16(ah, bhh[q], d[q], 0, 0, 0);

        // lane-local fused activations + c/h update — only khi<2 lanes hold
        // real batches (D rows khi*4+r = 0-7); exec-masked single issue.
        if (khi < 2) {
            #pragma unroll
            for (int hh = 0; hh < 2; ++hh) {
                #pragma unroll
                for (int r = 0; r < 4; ++r) {
                    const float ei = exp2_raw(d[0 + hh][r]);
                    const float ef = exp2_raw(d[2 + hh][r]);
                    const float eg = exp2_raw(d[4 + hh][r]);
                    const float eo = exp2_raw(d[6 + hh][r]);
                    const float pf  = 1.0f + ef;
                    const float pig = (1.0f + ei) * (1.0f + eg);
                    const float num = fmaf(c[hh][r], pig, (1.0f - eg) * pf);
                    c[hh][r] = num * __builtin_amdgcn_rcpf(pf * pig);
                    const float ec = exp2_raw(-2.88539008f * c[hh][r]);
                    const float hv = (1.0f - ec) * __builtin_amdgcn_rcpf((1.0f + eo) * (1.0f + ec));
                    hlds[khi * 4 + r][hh * 16 + n16] = (_Float16)hv;
                }
            }
        }
        __builtin_amdgcn_wave_barrier();
    }

    // ---- MLP head: lane = (batch n16 [rows 8-15 are zeros], unit-quarter khi) ----
    __builtin_amdgcn_wave_barrier();
    float hr[32];
    #pragma unroll
    for (int q8 = 0; q8 < 4; ++q8) {
        const h8_t hv = *(const h8_t*)&hlds[n16][q8 * 8];
        #pragma unroll
        for (int e = 0; e < 8; ++e) hr[q8 * 8 + e] = (float)hv[e];
    }
    float rsum = 0.0f;
    #pragma unroll
    for (int u = 0; u < 16; ++u) {
        const int row = khi * 16 + u;
        float a = b1s[row];
        #pragma unroll
        for (int k = 0; k < 32; k += 2) {
            const float2 w = *(const float2*)&w1s[row * 34 + k];
            a = fmaf(w.x, hr[k], a);
            a = fmaf(w.y, hr[k + 1], a);
        }
        rsum = fmaf(fmaxf(a, 0.0f), w2s[row], rsum);
    }
    rsum += __shfl_xor(rsum, 16, 64);
    rsum += __shfl_xor(rsum, 32, 64);
    if (khi == 0 && n16 < NB) out[blockIdx.x * NB + n16] = rsum + b2[0];
}

extern "C" void kernel_launch(void* const* d_in, const int* in_sizes, int n_in,
                              void* d_out, int out_size, void* d_ws, size_t ws_size,
                              hipStream_t stream) {
    const float* x    = (const float*)d_in[0];
    const float* W_ih = (const float*)d_in[1];
    const float* W_hh = (const float*)d_in[2];
    const float* b_ih = (const float*)d_in[3];
    const float* b_hh = (const float*)d_in[4];
    const float* W1   = (const float*)d_in[5];
    const float* b1   = (const float*)d_in[6];
    const float* W2   = (const float*)d_in[7];
    const float* b2   = (const float*)d_in[8];
    float* out = (float*)d_out;

    const int B = in_sizes[0] / (TSTEPS * ISZ);   // 8192
    const int grid = B / NB;                      // 1024 one-wave blocks -> 1 wave/SIMD

    lstm_wave<<<grid, 64, 0, stream>>>(x, W_ih, W_hh, b_ih, b_hh,
                                       W1, b1, W2, b2, out);
}

// Round 23
// 146.037 us; speedup vs baseline: 1.1413x; 1.1413x over previous
//
#include <hip/hip_runtime.h>
#include <cstdint>

#define HSZ 32
#define TSTEPS 256
#define ISZ 6
#define NB 16

typedef _Float16 h8_t __attribute__((ext_vector_type(8)));
typedef float f4_t __attribute__((ext_vector_type(4)));

#if __has_builtin(__builtin_amdgcn_exp2f)
__device__ __forceinline__ float exp2_raw(float x) { return __builtin_amdgcn_exp2f(x); }
#else
__device__ __forceinline__ float exp2_raw(float x) { return __expf(0.69314718056f * x); }
#endif

// Round-23 = round-19 base (NB=16, best measured 150.9us) with the activation
// rewritten PHASE-ORDERED (SoA across the 8 (b,u) pairs). Evidence (r19 vs
// r22): per-wave step time ~constant (1519 vs 1707 cyc) despite 2x coverage /
// 0.5x activation work -> the step is an in-order SERIAL CHAIN, i.e. the
// compiler schedules activation pair-by-pair and each pair's ~100cyc dep
// chain blocks issue of the next. Phase order makes all 8 instances of each
// op class adjacent (independent) so issue never stalls mid-phase:
//   P1: 32 gate exp2s | P2: pf/pig/num/den | P3: 8 rcp | P4: c update + carg
//   P5: 8 c-exp2      | P6: 8 out rcp      | P7: mul+cvt+ds_write
// Same math as r19 (7 trans/pair, common-denominator form); weights
// pre-scaled by -log2e (g rows -2log2e); bias preset in C-operand.
__global__ __launch_bounds__(64, 2) void lstm_wave(
    const float* __restrict__ x,
    const float* __restrict__ W_ih,
    const float* __restrict__ W_hh,
    const float* __restrict__ b_ih,
    const float* __restrict__ b_hh,
    const float* __restrict__ W1,
    const float* __restrict__ b1,
    const float* __restrict__ W2,
    const float* __restrict__ b2,
    float* __restrict__ out)
{
    __shared__ __align__(16) _Float16 hlds[NB][40];   // h state, 80B rows (16B-aligned)
    __shared__ float w1s[64 * 34];                    // stride 34: even + conflict-free
    __shared__ float b1s[64];
    __shared__ float w2s[64];

    const int lane = threadIdx.x;
    const int n16  = lane & 15;
    const int khi  = lane >> 4;

    // ---- one-time staging ----
    for (int i = lane; i < 64 * HSZ; i += 64) w1s[(i >> 5) * 34 + (i & 31)] = W1[i];
    b1s[lane] = b1[lane];
    w2s[lane] = W2[lane];
    #pragma unroll
    for (int i = 0; i < 5; ++i) ((unsigned int*)hlds)[lane + i * 64] = 0u;  // h0 = 0

    // B-fragments + bias, pre-scaled. Tile q: q0,1=i q2,3=f q4,5=g q6,7=o.
    const float LOG2E = 1.44269504f;
    h8_t bhh[8], bih[8];
    f4_t bias4[8];
    #pragma unroll
    for (int q = 0; q < 8; ++q) {
        const int grow = q * 16 + n16;
        const float s = (q == 4 || q == 5) ? (-2.0f * LOG2E) : (-LOG2E);
        const float4* p = (const float4*)(W_hh + grow * HSZ + khi * 8);
        const float4 a = p[0], b = p[1];
        bhh[q][0] = (_Float16)(s * a.x); bhh[q][1] = (_Float16)(s * a.y);
        bhh[q][2] = (_Float16)(s * a.z); bhh[q][3] = (_Float16)(s * a.w);
        bhh[q][4] = (_Float16)(s * b.x); bhh[q][5] = (_Float16)(s * b.y);
        bhh[q][6] = (_Float16)(s * b.z); bhh[q][7] = (_Float16)(s * b.w);
        const float bb = s * (b_ih[grow] + b_hh[grow]);
        bias4[q][0] = bb; bias4[q][1] = bb; bias4[q][2] = bb; bias4[q][3] = bb;
        bih[q][0] = (_Float16)0; bih[q][1] = (_Float16)0;
        bih[q][2] = (_Float16)0; bih[q][3] = (_Float16)0;
        bih[q][4] = (_Float16)0; bih[q][5] = (_Float16)0;
        bih[q][6] = (_Float16)0; bih[q][7] = (_Float16)0;
        if (khi == 0) {
            const float2* pi = (const float2*)(W_ih + grow * ISZ);
            const float2 i0 = pi[0], i1 = pi[1], i2 = pi[2];
            bih[q][0] = (_Float16)(s * i0.x); bih[q][1] = (_Float16)(s * i0.y);
            bih[q][2] = (_Float16)(s * i1.x); bih[q][3] = (_Float16)(s * i1.y);
            bih[q][4] = (_Float16)(s * i2.x); bih[q][5] = (_Float16)(s * i2.y);
        }
    }

    // x stream for batch n16 (all khi lanes load same addr -> broadcast).
    const float* xb = x + (size_t)(blockIdx.x * NB + n16) * (TSTEPS * ISZ);
    float2 xa0 = ((const float2*)xb)[0], xa1 = ((const float2*)xb)[1], xa2 = ((const float2*)xb)[2];
    const float2* pn1 = (const float2*)(xb + ISZ);
    float2 xn0 = pn1[0], xn1 = pn1[1], xn2 = pn1[2];

    float cc[8] = {0.f, 0.f, 0.f, 0.f, 0.f, 0.f, 0.f, 0.f};  // c for pair p=(hh<<2)|r

    __builtin_amdgcn_wave_barrier();

    for (int t = 0; t < TSTEPS; ++t) {
        // A-fragments
        const h8_t ah = *(const h8_t*)&hlds[n16][khi * 8];
        h8_t ax;
        ax[0] = (_Float16)xa0.x; ax[1] = (_Float16)xa0.y;
        ax[2] = (_Float16)xa1.x; ax[3] = (_Float16)xa1.y;
        ax[4] = (_Float16)xa2.x; ax[5] = (_Float16)xa2.y;
        ax[6] = (_Float16)0;     ax[7] = (_Float16)0;
        xa0 = xn0; xa1 = xn1; xa2 = xn2;
        const int tn = (t + 2 < TSTEPS) ? (t + 2) : (TSTEPS - 1);
        const float2* pn = (const float2*)(xb + tn * ISZ);
        xn0 = pn[0]; xn1 = pn[1]; xn2 = pn[2];

        // 16 MFMAs: x-part (K-padded, bias preset) then h-part chained.
        f4_t d[8];
        #pragma unroll
        for (int q = 0; q < 8; ++q)
            d[q] = __builtin_amdgcn_mfma_f32_16x16x32_f16(ax, bih[q], bias4[q], 0, 0, 0);
        #pragma unroll
        for (int q = 0; q < 8; ++q)
            d[q] = __builtin_amdgcn_mfma_f32_16x16x32_f16(ah, bhh[q], d[q], 0, 0, 0);

        // ---- phase-ordered activation over pairs p = hh*4 + r ----
        float ei[8], ef[8], eg[8], eo[8];
        #pragma unroll
        for (int p = 0; p < 8; ++p) {               // P1: 32 gate exp2s
            const int hh = p >> 2, r = p & 3;
            ei[p] = exp2_raw(d[0 + hh][r]);
            ef[p] = exp2_raw(d[2 + hh][r]);
            eg[p] = exp2_raw(d[4 + hh][r]);
            eo[p] = exp2_raw(d[6 + hh][r]);
        }
        float cn[8], den[8];
        #pragma unroll
        for (int p = 0; p < 8; ++p) {               // P2: numerators/denominators
            const float pf  = 1.0f + ef[p];
            const float pig = (1.0f + ei[p]) * (1.0f + eg[p]);
            cn[p]  = fmaf(cc[p], pig, (1.0f - eg[p]) * pf);
            den[p] = pf * pig;
        }
        #pragma unroll
        for (int p = 0; p < 8; ++p)                 // P3: 8 rcps
            den[p] = __builtin_amdgcn_rcpf(den[p]);
        float carg[8];
        #pragma unroll
        for (int p = 0; p < 8; ++p) {               // P4: c update + exp2 args
            cc[p]   = cn[p] * den[p];
            carg[p] = -2.88539008f * cc[p];
        }
        float ec[8];
        #pragma unroll
        for (int p = 0; p < 8; ++p)                 // P5: 8 c-exp2s
            ec[p] = exp2_raw(carg[p]);
        float rr[8];
        #pragma unroll
        for (int p = 0; p < 8; ++p)                 // P6: 8 output rcps
            rr[p] = __builtin_amdgcn_rcpf((1.0f + eo[p]) * (1.0f + ec[p]));
        #pragma unroll
        for (int p = 0; p < 8; ++p) {               // P7: h + writes
            const int hh = p >> 2, r = p & 3;
            const float hv = (1.0f - ec[p]) * rr[p];
            hlds[khi * 4 + r][hh * 16 + n16] = (_Float16)hv;
        }
        __builtin_amdgcn_wave_barrier();
    }

    // ---- MLP head: lane = (batch n16, unit-quarter khi) ----
    __builtin_amdgcn_wave_barrier();
    float hr[32];
    #pragma unroll
    for (int q8 = 0; q8 < 4; ++q8) {
        const h8_t hv = *(const h8_t*)&hlds[n16][q8 * 8];
        #pragma unroll
        for (int e = 0; e < 8; ++e) hr[q8 * 8 + e] = (float)hv[e];
    }
    float rsum = 0.0f;
    #pragma unroll
    for (int u = 0; u < 16; ++u) {
        const int row = khi * 16 + u;
        float a = b1s[row];
        #pragma unroll
        for (int k = 0; k < 32; k += 2) {
            const float2 w = *(const float2*)&w1s[row * 34 + k];
            a = fmaf(w.x, hr[k], a);
            a = fmaf(w.y, hr[k + 1], a);
        }
        rsum = fmaf(fmaxf(a, 0.0f), w2s[row], rsum);
    }
    rsum += __shfl_xor(rsum, 16, 64);
    rsum += __shfl_xor(rsum, 32, 64);
    if (khi == 0) out[blockIdx.x * NB + n16] = rsum + b2[0];
}

extern "C" void kernel_launch(void* const* d_in, const int* in_sizes, int n_in,
                              void* d_out, int out_size, void* d_ws, size_t ws_size,
                              hipStream_t stream) {
    const float* x    = (const float*)d_in[0];
    const float* W_ih = (const float*)d_in[1];
    const float* W_hh = (const float*)d_in[2];
    const float* b_ih = (const float*)d_in[3];
    const float* b_hh = (const float*)d_in[4];
    const float* W1   = (const float*)d_in[5];
    const float* b1   = (const float*)d_in[6];
    const float* W2   = (const float*)d_in[7];
    const float* b2   = (const float*)d_in[8];
    float* out = (float*)d_out;

    const int B = in_sizes[0] / (TSTEPS * ISZ);   // 8192
    const int grid = B / NB;                      // 512 one-wave blocks

    lstm_wave<<<grid, 64, 0, stream>>>(x, W_ih, W_hh, b_ih, b_hh,
                                       W1, b1, W2, b2, out);
}